// Round 14
// baseline (220.076 us; speedup 1.0000x reference)
//
#include <hip/hip_runtime.h>
#include <float.h>
#include <limits.h>

// N=131072, K=2048, D=64.
// Verified reference scheme R (rounds 5/7/9-13, absmax 0.0):
//   xsq: numpy NPY_SIMD-128 pairwise (8 vec-accs x 4 lanes + SSE3 hadd tree)
//   esq: scalar pairwise-8; dot: any fp32 order; dist=fl(fl(xsq+esq)-2dot);
//   argmin first-index.
// Round 14 = round 13 (folded -2e screen, no-esq screen, 2-pass + exact
// rescore + lossless fallback) with the T4 counted-vmcnt pipeline:
//   3 LDS buffers, 2-deep prefetch; per tile: s_waitcnt vmcnt(2) (stage t
//   only; stage t+1 stays in flight ACROSS the raw s_barrier), memfence,
//   issue STAGE(t+2), compute tile t. Last iteration peels to vmcnt(0).
// This removes the compiler's vmcnt(0) full drain before each __syncthreads
// (the ~40% stall: ~300cy L2 latency vs ~180cy phase compute).
#define D_DIM 64
#define K_CB  2048
#define BM    64
#define KT    64                // codes per staged tile (8 KB)
#define NT    (K_CB / KT)       // 32 tiles
#define MARGIN 2e-3f
#define CAND_CAP 24

typedef __attribute__((ext_vector_type(4))) float f32x4;
typedef __attribute__((ext_vector_type(8))) short s16x8;

__device__ __forceinline__ short f2bf(float f) {   // RN-even fp32->bf16 bits
  unsigned u = __builtin_bit_cast(unsigned, f);
  u += 0x7fffu + ((u >> 16) & 1u);
  return (short)(unsigned short)(u >> 16);
}

__device__ __forceinline__ void gload_lds16(const void* g, void* l) {
  __builtin_amdgcn_global_load_lds(
      (const __attribute__((address_space(1))) unsigned int*)g,
      (__attribute__((address_space(3))) unsigned int*)l, 16, 0, 0);
}

// prep: esq[k] (scalar-8 numpy order, verified) + bf16(-2*e) PRE-SWIZZLED:
//   cbh[k*64 + (d ^ ((k&7)<<3))] = bf16(-2*cb[k][d])
__global__ void __launch_bounds__(256) prep_kernel(const float* __restrict__ cb,
                                                   float* __restrict__ esq,
                                                   unsigned short* __restrict__ cbh) {
#pragma clang fp contract(off)
  int k = blockIdx.x * 256 + threadIdx.x;
  if (k >= K_CB) return;
  const float* row = cb + (size_t)k * D_DIM;
  float r[8];
#pragma unroll
  for (int j = 0; j < 8; ++j) { float v = row[j]; r[j] = v * v; }
#pragma unroll
  for (int i = 1; i < 8; ++i)
#pragma unroll
    for (int j = 0; j < 8; ++j) { float v = row[8 * i + j]; r[j] += v * v; }
  esq[k] = ((r[0] + r[1]) + (r[2] + r[3])) + ((r[4] + r[5]) + (r[6] + r[7]));
  unsigned short* o = cbh + (size_t)k * D_DIM;
  const int sw = (k & 7) << 3;
#pragma unroll
  for (int d = 0; d < D_DIM; ++d)
    o[d ^ sw] = (unsigned short)f2bf(-2.0f * row[d]);
}

__global__ void __launch_bounds__(256)
vq_mfma_kernel(const float* __restrict__ x,
               const float* __restrict__ cb,
               const float* __restrict__ esq,
               const unsigned short* __restrict__ cbh,
               float* __restrict__ out) {
#pragma clang fp contract(off)
  __shared__ float4 xs4[BM * 16];                 // 16 KB, float4-XOR swizzled
  __shared__ unsigned short bbuf[3][KT * D_DIM];  // 24 KB B triple-buffer
  __shared__ int   cand_s[BM * CAND_CAP];         // 6 KB
  __shared__ float xsq_s[BM];
  __shared__ float rowthr_s[BM];
  __shared__ int   cnt_s[BM];
  __shared__ int   bestk_s[BM];
  __shared__ int   ovf_rows[BM];
  __shared__ int   ovf_cnt;
  __shared__ float fb_v[4];
  __shared__ int   fb_k[4];

  const int tid  = threadIdx.x;
  const int lane = tid & 63;
  const int wave = tid >> 6;
  const int row0 = blockIdx.x * BM;

  // ---- stage x tile (coalesced float4), swizzle float4-col ^= (row>>2)&7 ----
  const float4* xg = (const float4*)(x + (size_t)row0 * D_DIM);
#pragma unroll
  for (int i = 0; i < 4; ++i) {
    int f = tid + i * 256;
    int row = f >> 4, c4 = f & 15;
    xs4[row * 16 + (c4 ^ ((row >> 2) & 7))] = xg[f];
  }
  if (tid == 0) ovf_cnt = 0;
  if (tid < BM) cnt_s[tid] = 0;
  __syncthreads();

  // ---- xsq per row: numpy NPY_SIMD-128 pairwise emulation (verified R5) ----
  if (tid < BM) {
    const int swz = 4 * ((tid >> 2) & 7);
    const float* xr = (const float*)xs4 + tid * 64;
    float s[4];
#pragma unroll
    for (int l = 0; l < 4; ++l) {
      float rj[8];
#pragma unroll
      for (int j = 0; j < 8; ++j) {
        float a = xr[(4 * j + l) ^ swz];
        float b = xr[(32 + 4 * j + l) ^ swz];
        float ta = a * a;
        float tb = b * b;
        rj[j] = ta + tb;
      }
      s[l] = ((rj[0] + rj[1]) + (rj[2] + rj[3])) +
             ((rj[4] + rj[5]) + (rj[6] + rj[7]));
    }
    xsq_s[tid] = (s[0] + s[1]) + (s[2] + s[3]);
  }

  // ---- A fragments: wave owns rows wave*16..wave*16+15 (m89-verified maps) ----
  s16x8 a0, a1;
  {
    const int arow = lane & 15;
    const int kgA = (lane >> 4) * 8;
    const int row = wave * 16 + arow;
    const int sw = (row >> 2) & 7;
    {
      int q0 = kgA >> 2;
      float4 f0 = xs4[row * 16 + (q0 ^ sw)];
      float4 f1 = xs4[row * 16 + ((q0 + 1) ^ sw)];
      a0[0] = f2bf(f0.x); a0[1] = f2bf(f0.y); a0[2] = f2bf(f0.z); a0[3] = f2bf(f0.w);
      a0[4] = f2bf(f1.x); a0[5] = f2bf(f1.y); a0[6] = f2bf(f1.z); a0[7] = f2bf(f1.w);
    }
    {
      int q0 = (32 + kgA) >> 2;
      float4 f0 = xs4[row * 16 + (q0 ^ sw)];
      float4 f1 = xs4[row * 16 + ((q0 + 1) ^ sw)];
      a1[0] = f2bf(f0.x); a1[1] = f2bf(f0.y); a1[2] = f2bf(f0.z); a1[3] = f2bf(f0.w);
      a1[4] = f2bf(f1.x); a1[5] = f2bf(f1.y); a1[6] = f2bf(f1.z); a1[7] = f2bf(f1.w);
    }
  }

  const int ccol = lane & 15;
  const int kg   = (lane >> 4) * 8;
  const int swb  = (ccol & 7) << 3;        // st*16 ≡ 0 mod 8 -> lane-constant

  // stage tile t into bbuf[b]: 8 KB = 2 x (wave-uniform 1KB dest + lane*16)
  // => 2 outstanding vmem ops per thread per STAGE.
  auto STAGE = [&](int t, int b) {
    const char* s0 = (const char*)cbh + (size_t)t * 8192 + wave * 2048 + lane * 16;
    char* d0 = (char*)&bbuf[b][0] + wave * 2048;
    gload_lds16(s0, d0);
    gload_lds16(s0 + 1024, d0 + 1024);
  };

  // ================= pass 1: per-row screen min (T4 pipeline) =================
  float minv[4];
  minv[0] = minv[1] = minv[2] = minv[3] = FLT_MAX;

  STAGE(0, 0);
  STAGE(1, 1);
  for (int t = 0; t < NT; ++t) {
    // wait for stage t only; stage t+1 stays in flight across the barrier
    if (t < NT - 1) asm volatile("s_waitcnt vmcnt(2)" ::: "memory");
    else            asm volatile("s_waitcnt vmcnt(0)" ::: "memory");
    __builtin_amdgcn_s_barrier();
    asm volatile("" ::: "memory");         // no LDS reads hoist above barrier
    if (t + 2 < NT) STAGE(t + 2, (t + 2) % 3);
    const unsigned short* B = &bbuf[t % 3][0];
#pragma unroll
    for (int st = 0; st < 4; ++st) {
      const unsigned short* bp = B + (st * 16 + ccol) * 64;
      s16x8 b0 = *(const s16x8*)(bp + (kg ^ swb));
      s16x8 b1 = *(const s16x8*)(bp + ((32 + kg) ^ swb));
      f32x4 acc = {0.f, 0.f, 0.f, 0.f};
      acc = __builtin_amdgcn_mfma_f32_16x16x32_bf16(a0, b0, acc, 0, 0, 0);
      acc = __builtin_amdgcn_mfma_f32_16x16x32_bf16(a1, b1, acc, 0, 0, 0);
#pragma unroll
      for (int r = 0; r < 4; ++r) minv[r] = fminf(minv[r], acc[r]);
    }
  }

  // per-row min across the 16 col-lanes (rows are wave-private)
#pragma unroll
  for (int r = 0; r < 4; ++r) {
    float v = minv[r];
#pragma unroll
    for (int m = 1; m <= 8; m <<= 1) v = fminf(v, __shfl_xor(v, m));
    minv[r] = v;
  }
  if ((lane & 15) == 0) {
#pragma unroll
    for (int r = 0; r < 4; ++r)
      rowthr_s[wave * 16 + (lane >> 4) * 4 + r] = minv[r] + MARGIN;
  }
  __syncthreads();

  float thr[4];
#pragma unroll
  for (int r = 0; r < 4; ++r)
    thr[r] = rowthr_s[wave * 16 + (lane >> 4) * 4 + r];

  // ====== pass 2: recompute (bit-identical), collect candidates ======
  STAGE(0, 0);
  STAGE(1, 1);
  for (int t = 0; t < NT; ++t) {
    if (t < NT - 1) asm volatile("s_waitcnt vmcnt(2)" ::: "memory");
    else            asm volatile("s_waitcnt vmcnt(0)" ::: "memory");
    __builtin_amdgcn_s_barrier();
    asm volatile("" ::: "memory");
    if (t + 2 < NT) STAGE(t + 2, (t + 2) % 3);
    const unsigned short* B = &bbuf[t % 3][0];
#pragma unroll
    for (int st = 0; st < 4; ++st) {
      const unsigned short* bp = B + (st * 16 + ccol) * 64;
      s16x8 b0 = *(const s16x8*)(bp + (kg ^ swb));
      s16x8 b1 = *(const s16x8*)(bp + ((32 + kg) ^ swb));
      f32x4 acc = {0.f, 0.f, 0.f, 0.f};
      acc = __builtin_amdgcn_mfma_f32_16x16x32_bf16(a0, b0, acc, 0, 0, 0);
      acc = __builtin_amdgcn_mfma_f32_16x16x32_bf16(a1, b1, acc, 0, 0, 0);
#pragma unroll
      for (int r = 0; r < 4; ++r) {
        if (acc[r] <= thr[r]) {
          int row = wave * 16 + (lane >> 4) * 4 + r;
          int pos = atomicAdd(&cnt_s[row], 1);
          if (pos < CAND_CAP) cand_s[row * CAND_CAP + pos] = t * 64 + st * 16 + ccol;
        }
      }
    }
  }
  __syncthreads();

  // ====== exact rescore (R-scheme), lex-(dist,k); 4 threads per row ======
  {
    const int row = tid >> 2, slot = tid & 3;
    const int cnt = cnt_s[row];
    if (cnt <= CAND_CAP) {
      const int swz = 4 * ((row >> 2) & 7);
      const float* xr = (const float*)xs4 + row * 64;
      const float xq = xsq_s[row];
      float bv = FLT_MAX; int bk = INT_MAX;
      for (int i = slot; i < cnt; i += 4) {
        int k = cand_s[row * CAND_CAP + i];
        const float* er = cb + (size_t)k * D_DIM;
        float a = 0.f;
#pragma unroll 8
        for (int d = 0; d < D_DIM; ++d) a = fmaf(xr[d ^ swz], er[d], a);
        float dist = (xq + esq[k]) - 2.0f * a;
        if (dist < bv || (dist == bv && k < bk)) { bv = dist; bk = k; }
      }
#pragma unroll
      for (int m = 1; m <= 2; m <<= 1) {
        float ov = __shfl_xor(bv, m); int ok = __shfl_xor(bk, m);
        if (ov < bv || (ov == bv && ok < bk)) { bv = ov; bk = ok; }
      }
      if (slot == 0) bestk_s[row] = bk;
    }
  }
  if (tid < BM && cnt_s[tid] > CAND_CAP) {
    int p = atomicAdd(&ovf_cnt, 1);
    ovf_rows[p] = tid;
  }
  __syncthreads();

  // ====== lossless overflow fallback: block-cooperative full scan ======
  {
    const int novf = ovf_cnt;
    for (int i = 0; i < novf; ++i) {
      const int row = ovf_rows[i];
      const int swz = 4 * ((row >> 2) & 7);
      const float* xr = (const float*)xs4 + row * 64;
      const float xq = xsq_s[row];
      float bv = FLT_MAX; int bk = INT_MAX;
      for (int k = tid; k < K_CB; k += 256) {
        const float* er = cb + (size_t)k * D_DIM;
        float a = 0.f;
#pragma unroll 8
        for (int d = 0; d < D_DIM; ++d) a = fmaf(xr[d ^ swz], er[d], a);
        float dist = (xq + esq[k]) - 2.0f * a;
        if (dist < bv || (dist == bv && k < bk)) { bv = dist; bk = k; }
      }
#pragma unroll
      for (int m = 1; m <= 32; m <<= 1) {
        float ov = __shfl_xor(bv, m); int ok = __shfl_xor(bk, m);
        if (ov < bv || (ov == bv && ok < bk)) { bv = ov; bk = ok; }
      }
      if (lane == 0) { fb_v[wave] = bv; fb_k[wave] = bk; }
      __syncthreads();
      if (tid == 0) {
        float BV = fb_v[0]; int BK = fb_k[0];
#pragma unroll
        for (int w = 1; w < 4; ++w)
          if (fb_v[w] < BV || (fb_v[w] == BV && fb_k[w] < BK)) { BV = fb_v[w]; BK = fb_k[w]; }
        bestk_s[row] = BK;
      }
      __syncthreads();
    }
  }
  __syncthreads();

  // ---- gather: out[row] = codebook[bestk[row]], coalesced float4 ----
  const float4* cb4 = (const float4*)cb;
  float4* out4 = (float4*)out + (size_t)row0 * 16;
#pragma unroll
  for (int i = 0; i < 4; ++i) {
    int f = tid + i * 256;
    int row = f >> 4, c4 = f & 15;
    out4[f] = cb4[(size_t)bestk_s[row] * 16 + c4];
  }
}

extern "C" void kernel_launch(void* const* d_in, const int* in_sizes, int n_in,
                              void* d_out, int out_size, void* d_ws, size_t ws_size,
                              hipStream_t stream) {
  const float* x  = (const float*)d_in[0];   // [N, 64] fp32
  const float* cb = (const float*)d_in[1];   // [2048, 64] fp32
  float* out = (float*)d_out;                // [N, 64] fp32
  float* esq = (float*)d_ws;                 // [2048] fp32
  unsigned short* cbh = (unsigned short*)d_ws + 4096;  // swizzled bf16(-2e), 256 KB

  const int N = in_sizes[0] / D_DIM;         // 131072

  prep_kernel<<<(K_CB + 255) / 256, 256, 0, stream>>>(cb, esq, cbh);
  vq_mfma_kernel<<<N / BM, 256, 0, stream>>>(x, cb, esq, cbh, out);
}